// Round 1
// baseline (260.192 us; speedup 1.0000x reference)
//
#include <hip/hip_runtime.h>

// Problem constants (fixed by reference):
//   x: [131072, 64] f32, W1: [32,128,64] f32, b1: [32,128], W2: [32,128], b2: [32]
//   out[n,o] = sum_h silu(sum_w x[n,w]*W1[o,h,w] + b1[o,h]) * W2[o,h] + b2[o]
#define NC    131072
#define WDIM  64
#define ODIM  32
#define HDIM  128

typedef __attribute__((ext_vector_type(8))) short bf16x8;   // 8 bf16 = 4 VGPRs (MFMA A/B frag)
typedef __attribute__((ext_vector_type(4))) float f32x4;    // MFMA C/D frag
typedef __attribute__((ext_vector_type(4))) float flt4;

__device__ __forceinline__ short f2bf(float f) {
    union { float f; unsigned u; } v; v.f = f;
    unsigned r = (v.u + 0x7FFFu + ((v.u >> 16) & 1u)) >> 16;   // RNE
    return (short)r;
}

// ---------------- prep: W1 [O][H][W] f32 -> frag-major bf16 in d_ws ----------------
// dst element (o, frag = t*2+k2, lane, i) = W1[o][t*16 + (lane&15)][k2*32 + (lane>>4)*8 + i]
// so the main kernel's B-fragment ds_read is a linear lane*16B read (conflict-free) and
// staging can use global_load_lds (linear dest = wave base + lane*16).
__global__ void prep_w1_kernel(const float* __restrict__ W1, short* __restrict__ w1f) {
    int tid  = blockIdx.x * 256 + threadIdx.x;   // 32768 threads total
    int lane = tid & 63;
    int frag = (tid >> 6) & 15;                  // t*2 + k2
    int o    = tid >> 10;
    int t    = frag >> 1;
    int k2   = frag & 1;
    int col  = lane & 15;
    int kq   = lane >> 4;
    const float* src = W1 + ((size_t)(o * HDIM + t * 16 + col) * WDIM + k2 * 32 + kq * 8);
    bf16x8 v;
    #pragma unroll
    for (int i = 0; i < 8; ++i) v[i] = f2bf(src[i]);
    *reinterpret_cast<bf16x8*>(w1f + (size_t)tid * 8) = v;
}

// ---------------- main kernel ----------------
__device__ __forceinline__ void async16(void* lds_dst, const void* g_src) {
    __builtin_amdgcn_global_load_lds(
        (const __attribute__((address_space(1))) unsigned int*)g_src,
        (__attribute__((address_space(3))) unsigned int*)lds_dst,
        16, 0, 0);
}

__global__ __launch_bounds__(256, 2)
void swr_main(const float* __restrict__ x, const short* __restrict__ w1f,
              const float* __restrict__ b1, const float* __restrict__ w2,
              const float* __restrict__ b2, float* __restrict__ out)
{
    __shared__ short w1lds[2 * 8192];            // 2 x 16KB double buffer for W1[o] bf16 frags
    const int tid  = threadIdx.x;
    const int lane = tid & 63;
    const int wid  = tid >> 6;                   // wave 0..3
    const int col  = lane & 15;
    const int kq   = lane >> 4;
    const size_t rowbase = (size_t)blockIdx.x * 256 + (size_t)wid * 64;

    // A fragments (x rows, bf16) held in registers for ALL 32 o's:
    // stripe s covers rows rowbase+s*16..+15; lane holds row (lane&15), k = kq*8.. (8 contig)
    bf16x8 afrag[4][2];
    #pragma unroll
    for (int s = 0; s < 4; ++s) {
        #pragma unroll
        for (int k2 = 0; k2 < 2; ++k2) {
            const float* p = x + (rowbase + s * 16 + col) * WDIM + k2 * 32 + kq * 8;
            flt4 lo = *reinterpret_cast<const flt4*>(p);
            flt4 hi = *reinterpret_cast<const flt4*>(p + 4);
            bf16x8 a;
            a[0] = f2bf(lo[0]); a[1] = f2bf(lo[1]); a[2] = f2bf(lo[2]); a[3] = f2bf(lo[3]);
            a[4] = f2bf(hi[0]); a[5] = f2bf(hi[1]); a[6] = f2bf(hi[2]); a[7] = f2bf(hi[3]);
            afrag[s][k2] = a;
        }
    }

    // stage o=0 into buffer 0 (each wave stages 4 of the 16 frags; 1KB per frag)
    {
        const short* g = w1f;
        #pragma unroll
        for (int f = 0; f < 4; ++f) {
            int frag = wid * 4 + f;
            async16(&w1lds[frag * 512], g + frag * 512 + lane * 8);
        }
    }
    __syncthreads();   // implicit vmcnt(0) drain before s_barrier

    for (int o = 0; o < ODIM; ++o) {
        const short* cur = &w1lds[(o & 1) * 8192];
        if (o + 1 < ODIM) {                      // prefetch next o into other buffer
            const short* g = w1f + (size_t)(o + 1) * 8192;
            short* nb = &w1lds[((o + 1) & 1) * 8192];
            #pragma unroll
            for (int f = 0; f < 4; ++f) {
                int frag = wid * 4 + f;
                async16(nb + frag * 512, g + frag * 512 + lane * 8);
            }
        }

        float b1v[8], w2v[8];
        #pragma unroll
        for (int t = 0; t < 8; ++t) {
            b1v[t] = b1[o * HDIM + t * 16 + col];   // lane's h-column bias / weight
            w2v[t] = w2[o * HDIM + t * 16 + col];
        }
        const float b2o = b2[o];

        float part[4][4];
        #pragma unroll
        for (int s = 0; s < 4; ++s)
            #pragma unroll
            for (int r = 0; r < 4; ++r) part[s][r] = 0.f;

        #pragma unroll
        for (int t = 0; t < 8; ++t) {
            bf16x8 bf0 = *reinterpret_cast<const bf16x8*>(cur + (t * 2 + 0) * 512 + lane * 8);
            bf16x8 bf1 = *reinterpret_cast<const bf16x8*>(cur + (t * 2 + 1) * 512 + lane * 8);
            #pragma unroll
            for (int s = 0; s < 4; ++s) {
                f32x4 acc = { b1v[t], b1v[t], b1v[t], b1v[t] };   // fold b1 into acc init
                acc = __builtin_amdgcn_mfma_f32_16x16x32_bf16(afrag[s][0], bf0, acc, 0, 0, 0);
                acc = __builtin_amdgcn_mfma_f32_16x16x32_bf16(afrag[s][1], bf1, acc, 0, 0, 0);
                #pragma unroll
                for (int r = 0; r < 4; ++r) {       // silu + second-layer fma (fp32)
                    float z  = acc[r];
                    float e  = __builtin_amdgcn_exp2f(z * -1.44269504088896f);
                    float sg = __builtin_amdgcn_rcpf(1.0f + e);
                    part[s][r] = __builtin_fmaf(z * sg, w2v[t], part[s][r]);
                }
            }
        }

        // reduce the 16 h-columns (lane bits 0..3) and store one value per row
        #pragma unroll
        for (int s = 0; s < 4; ++s) {
            float v[4];
            #pragma unroll
            for (int r = 0; r < 4; ++r) {
                float u = part[s][r];
                u += __shfl_xor(u, 1);
                u += __shfl_xor(u, 2);
                u += __shfl_xor(u, 4);
                u += __shfl_xor(u, 8);
                v[r] = u;                            // full sum over 128 h, row (lane>>4)*4+r
            }
            float sel = (lane & 1) ? ((lane & 2) ? v[3] : v[1])
                                   : ((lane & 2) ? v[2] : v[0]);
            if ((lane & 12) == 0) {                  // 16 active lanes cover 16 distinct rows
                int rowis = (lane >> 4) * 4 + (lane & 3);
                out[(rowbase + s * 16 + rowis) * ODIM + o] = sel + b2o;
            }
        }
        __syncthreads();   // prefetched buffer complete + safe to overwrite cur next iter
    }
}

extern "C" void kernel_launch(void* const* d_in, const int* in_sizes, int n_in,
                              void* d_out, int out_size, void* d_ws, size_t ws_size,
                              hipStream_t stream)
{
    const float* x  = (const float*)d_in[0];
    const float* W1 = (const float*)d_in[1];
    const float* b1 = (const float*)d_in[2];
    const float* w2 = (const float*)d_in[3];
    const float* b2 = (const float*)d_in[4];
    float* out = (float*)d_out;
    short* w1f = (short*)d_ws;   // 32*128*64 bf16 = 512 KB frag-major W1

    hipLaunchKernelGGL(prep_w1_kernel, dim3(128), dim3(256), 0, stream, W1, w1f);
    hipLaunchKernelGGL(swr_main, dim3(NC / 256), dim3(256), 0, stream,
                       x, w1f, b1, w2, b2, out);
}

// Round 2
// 237.309 us; speedup vs baseline: 1.0964x; 1.0964x over previous
//
#include <hip/hip_runtime.h>

// out[n,o] = sum_h silu(sum_w x[n,w]*W1[o,h,w] + b1[o,h]) * W2[o,h] + b2[o]
//   x: [131072, 64] f32, W1: [32,128,64] f32, b1: [32,128], W2: [32,128], b2: [32]
//
// Strategy: bf16 MFMA for layer 1 (fp32 accum), fused silu + layer-2 fma, shfl reduce.
// Constant folding: W1' = -log2e*W1, b1' = -log2e*b1 (MFMA emits m = -z*log2e),
// w2' = -ln2*w2. Then silu(z)*w2 = m*rcp(1+exp2(m))*w2'  -- saves one mul/activation.
#define NC    131072
#define WDIM  64
#define ODIM  32
#define HDIM  128
#define LOG2E 1.4426950408889634f
#define LN2   0.6931471805599453f

typedef __attribute__((ext_vector_type(8))) short bf16x8;   // MFMA A/B frag (4 VGPRs)
typedef __attribute__((ext_vector_type(4))) float f32x4;    // MFMA C/D frag
typedef __attribute__((ext_vector_type(4))) float flt4;

__device__ __forceinline__ short f2bf(float f) {
    union { float f; unsigned u; } v; v.f = f;
    unsigned r = (v.u + 0x7FFFu + ((v.u >> 16) & 1u)) >> 16;   // RNE
    return (short)r;
}

// ---------------- prep: W1 -> frag-major bf16 (scaled); b1,w2 -> scaled f32 copies ----
// w1f element (o, frag=t*2+k2, lane, i) = -log2e * W1[o][t*16+(lane&15)][k2*32+(lane>>4)*8+i]
__global__ void prep_kernel(const float* __restrict__ W1, const float* __restrict__ b1,
                            const float* __restrict__ w2, short* __restrict__ w1f,
                            float* __restrict__ b1s, float* __restrict__ w2s) {
    if (blockIdx.x < 128) {
        int tid  = blockIdx.x * 256 + threadIdx.x;   // 32768 threads
        int lane = tid & 63;
        int frag = (tid >> 6) & 15;
        int o    = tid >> 10;
        int t    = frag >> 1;
        int k2   = frag & 1;
        const float* src = W1 + ((size_t)(o * HDIM + t * 16 + (lane & 15)) * WDIM
                                 + k2 * 32 + (lane >> 4) * 8);
        bf16x8 v;
        #pragma unroll
        for (int i = 0; i < 8; ++i) v[i] = f2bf(src[i] * -LOG2E);
        *reinterpret_cast<bf16x8*>(w1f + (size_t)tid * 8) = v;
    } else if (blockIdx.x < 144) {
        int idx = (blockIdx.x - 128) * 256 + threadIdx.x;    // 4096 = O*H
        b1s[idx] = b1[idx] * -LOG2E;
    } else {
        int idx = (blockIdx.x - 144) * 256 + threadIdx.x;
        w2s[idx] = w2[idx] * -LN2;
    }
}

__device__ __forceinline__ void async16(void* lds_dst, const void* g_src) {
    __builtin_amdgcn_global_load_lds(
        (const __attribute__((address_space(1))) unsigned int*)g_src,
        (__attribute__((address_space(3))) unsigned int*)lds_dst,
        16, 0, 0);
}

__global__ __launch_bounds__(256, 4)
void swr_main(const float* __restrict__ x, const short* __restrict__ w1f,
              const float* __restrict__ b1s, const float* __restrict__ w2s,
              const float* __restrict__ b2, float* __restrict__ out)
{
    __shared__ short w1lds[2 * 8192];            // double buffer: 16KB per o
    const int tid  = threadIdx.x;
    const int lane = tid & 63;
    const int wid  = tid >> 6;
    const int col  = lane & 15;
    const int kq   = lane >> 4;
    const size_t rowbase = (size_t)blockIdx.x * 128 + (size_t)wid * 32;

    // A fragments: 2 stripes x 16 rows, bf16, kept in registers for all 32 o's
    bf16x8 afrag[2][2];
    #pragma unroll
    for (int s = 0; s < 2; ++s) {
        #pragma unroll
        for (int k2 = 0; k2 < 2; ++k2) {
            const float* p = x + (rowbase + s * 16 + col) * WDIM + k2 * 32 + kq * 8;
            flt4 lo = *reinterpret_cast<const flt4*>(p);
            flt4 hi = *reinterpret_cast<const flt4*>(p + 4);
            bf16x8 a;
            a[0] = f2bf(lo[0]); a[1] = f2bf(lo[1]); a[2] = f2bf(lo[2]); a[3] = f2bf(lo[3]);
            a[4] = f2bf(hi[0]); a[5] = f2bf(hi[1]); a[6] = f2bf(hi[2]); a[7] = f2bf(hi[3]);
            afrag[s][k2] = a;
        }
    }

    // stage o=0 into buffer 0 (wave stages frags wid*4..wid*4+3; 1KB each, linear dest)
    {
        #pragma unroll
        for (int f = 0; f < 4; ++f) {
            int frag = wid * 4 + f;
            async16(&w1lds[frag * 512], w1f + frag * 512 + lane * 8);
        }
    }
    __syncthreads();

    for (int o = 0; o < ODIM; ++o) {
        const short* cur = &w1lds[(o & 1) * 8192];
        if (o + 1 < ODIM) {
            const short* g = w1f + (size_t)(o + 1) * 8192;
            short* nb = &w1lds[((o + 1) & 1) * 8192];
            #pragma unroll
            for (int f = 0; f < 4; ++f) {
                int frag = wid * 4 + f;
                async16(nb + frag * 512, g + frag * 512 + lane * 8);
            }
        }

        float b1v[8], w2v[8];
        #pragma unroll
        for (int t = 0; t < 8; ++t) {
            b1v[t] = b1s[o * HDIM + t * 16 + col];
            w2v[t] = w2s[o * HDIM + t * 16 + col];
        }
        const float b2o = b2[o];

        float part[2][4];
        #pragma unroll
        for (int s = 0; s < 2; ++s)
            #pragma unroll
            for (int r = 0; r < 4; ++r) part[s][r] = 0.f;

        #pragma unroll
        for (int t = 0; t < 8; ++t) {
            bf16x8 bf0 = *reinterpret_cast<const bf16x8*>(cur + (t * 2 + 0) * 512 + lane * 8);
            bf16x8 bf1 = *reinterpret_cast<const bf16x8*>(cur + (t * 2 + 1) * 512 + lane * 8);
            #pragma unroll
            for (int s = 0; s < 2; ++s) {
                f32x4 acc = { b1v[t], b1v[t], b1v[t], b1v[t] };
                acc = __builtin_amdgcn_mfma_f32_16x16x32_bf16(afrag[s][0], bf0, acc, 0, 0, 0);
                acc = __builtin_amdgcn_mfma_f32_16x16x32_bf16(afrag[s][1], bf1, acc, 0, 0, 0);
                #pragma unroll
                for (int r = 0; r < 4; ++r) {
                    float m  = acc[r];                                  // -z*log2e
                    float e  = __builtin_amdgcn_exp2f(m);               // exp(-z)
                    float sg = __builtin_amdgcn_rcpf(1.0f + e);         // sigmoid(z)
                    part[s][r] = __builtin_fmaf(m * sg, w2v[t], part[s][r]);
                }
            }
        }

        // reduce 16 h-columns (lane bits 0..3); one value per row
        #pragma unroll
        for (int s = 0; s < 2; ++s) {
            float v[4];
            #pragma unroll
            for (int r = 0; r < 4; ++r) {
                float u = part[s][r];
                u += __shfl_xor(u, 1);
                u += __shfl_xor(u, 2);
                u += __shfl_xor(u, 4);
                u += __shfl_xor(u, 8);
                v[r] = u;
            }
            float sel = (lane & 1) ? ((lane & 2) ? v[3] : v[1])
                                   : ((lane & 2) ? v[2] : v[0]);
            if ((lane & 12) == 0) {
                int rowis = kq * 4 + (lane & 3);
                out[(rowbase + s * 16 + rowis) * ODIM + o] = sel + b2o;
            }
        }
        __syncthreads();
    }
}

extern "C" void kernel_launch(void* const* d_in, const int* in_sizes, int n_in,
                              void* d_out, int out_size, void* d_ws, size_t ws_size,
                              hipStream_t stream)
{
    const float* x  = (const float*)d_in[0];
    const float* W1 = (const float*)d_in[1];
    const float* b1 = (const float*)d_in[2];
    const float* w2 = (const float*)d_in[3];
    const float* b2 = (const float*)d_in[4];
    float* out = (float*)d_out;
    short* w1f = (short*)d_ws;                               // 512 KB
    float* b1s = (float*)((char*)d_ws + 512 * 1024);         // 16 KB
    float* w2s = (float*)((char*)d_ws + 528 * 1024);         // 16 KB

    hipLaunchKernelGGL(prep_kernel, dim3(160), dim3(256), 0, stream,
                       W1, b1, w2, w1f, b1s, w2s);
    hipLaunchKernelGGL(swr_main, dim3(NC / 128), dim3(256), 0, stream,
                       x, w1f, b1s, w2s, b2, out);
}